// Round 8
// baseline (251.213 us; speedup 1.0000x reference)
//
#include <hip/hip_runtime.h>
#include <cstdint>
#include <cstddef>

typedef _Float16 half_t;
typedef _Float16 half8 __attribute__((ext_vector_type(8)));
typedef float floatx4 __attribute__((ext_vector_type(4)));

#define E_ 8
#define D_ 512
#define H_ 2048
#define NTOK 1024
#define NP 2048            // NTOK * top_k
#define TM 64              // GEMM M-tile rows
#define MAX_TILES 40       // 2048/64 + 8 experts

__device__ __forceinline__ float gelu_f(float x) {
    return 0.5f * x * (1.0f + erff(x * 0.7071067811865476f));
}

__device__ __forceinline__ half8 cvt8(floatx4 a, floatx4 b) {
    half8 h = { (half_t)a[0], (half_t)a[1], (half_t)a[2], (half_t)a[3],
                (half_t)b[0], (half_t)b[1], (half_t)b[2], (half_t)b[3] };
    return h;
}

// ---------------- gate: logits only ----------------
__global__ __launch_bounds__(256) void gate_kernel(
        const float* __restrict__ inp, const float* __restrict__ gate_w,
        const float* __restrict__ gate_b, float* __restrict__ logits) {
    int n = blockIdx.x * 4 + (threadIdx.x >> 6);
    int lane = threadIdx.x & 63;
    const floatx4* xr = (const floatx4*)(inp + (size_t)n * D_);
    floatx4 x0 = xr[lane * 2], x1 = xr[lane * 2 + 1];
    #pragma unroll
    for (int e = 0; e < E_; e++) {
        const floatx4* gr = (const floatx4*)(gate_w + (size_t)e * D_);
        floatx4 g0 = gr[lane * 2], g1 = gr[lane * 2 + 1];
        float p = x0[0]*g0[0] + x0[1]*g0[1] + x0[2]*g0[2] + x0[3]*g0[3]
                + x1[0]*g1[0] + x1[1]*g1[1] + x1[2]*g1[2] + x1[3]*g1[3];
        #pragma unroll
        for (int m = 1; m < 64; m <<= 1) p += __shfl_xor(p, m);
        if (lane == 0) logits[(size_t)n * E_ + e] = p + gate_b[e];
    }
}

// ---------------- plan: top2/softmax/hist/offsets/tiles/pos maps ----------------
__global__ __launch_bounds__(256) void plan_kernel(
        const float* __restrict__ logits, float* __restrict__ score,
        int* __restrict__ idx, int* __restrict__ pos_of_pair,
        int* __restrict__ tok_of_pos,
        int* __restrict__ tile_e, int* __restrict__ tile_row0,
        int* __restrict__ tile_cnt, int* __restrict__ ntiles) {
    __shared__ int cnt_s[E_], off_s[E_ + 1], cur_s[E_];
    int tid = threadIdx.x;
    if (tid < E_) { cnt_s[tid] = 0; cur_s[tid] = 0; }
    __syncthreads();
    int my_e[4][2];
    #pragma unroll
    for (int i = 0; i < 4; i++) {
        int n = tid + i * 256;
        float l[E_];
        #pragma unroll
        for (int e = 0; e < E_; e++) l[e] = logits[(size_t)n * E_ + e];
        int e0 = 0; float v0 = l[0];
        #pragma unroll
        for (int e = 1; e < E_; e++) if (l[e] > v0) { v0 = l[e]; e0 = e; }
        int e1 = -1; float v1 = -3.4e38f;
        #pragma unroll
        for (int e = 0; e < E_; e++) if (e != e0 && l[e] > v1) { v1 = l[e]; e1 = e; }
        float s1 = expf(v1 - v0);
        float den = 1.0f + s1;
        score[2 * n]     = 1.0f / den;
        score[2 * n + 1] = s1 / den;
        idx[2 * n]     = e0;
        idx[2 * n + 1] = e1;
        atomicAdd(&cnt_s[e0], 1);
        atomicAdd(&cnt_s[e1], 1);
        my_e[i][0] = e0; my_e[i][1] = e1;
    }
    __syncthreads();
    if (tid == 0) {
        int o = 0;
        #pragma unroll
        for (int e = 0; e < E_; e++) { off_s[e] = o; o += cnt_s[e]; }
        off_s[E_] = o;
        int t = 0;
        for (int e = 0; e < E_; e++) {
            int c = cnt_s[e];
            int nt = (c + TM - 1) / TM;
            for (int i = 0; i < nt; i++) {
                tile_e[t] = e;
                tile_row0[t] = off_s[e] + i * TM;
                int rem = c - i * TM;
                tile_cnt[t] = rem < TM ? rem : TM;
                t++;
            }
        }
        ntiles[0] = t;
    }
    __syncthreads();
    #pragma unroll
    for (int i = 0; i < 4; i++) {
        #pragma unroll
        for (int k = 0; k < 2; k++) {
            int pp = (tid + i * 256) * 2 + k;
            int e = my_e[i][k];
            int r = atomicAdd(&cur_s[e], 1);
            int pos = off_s[e] + r;
            pos_of_pair[pp] = pos;
            tok_of_pos[pos] = pp >> 1;
        }
    }
}

// ---------------- GEMM1 (direct, no LDS, no barriers) ----------------
// Y1 = gelu(inp[tok] @ W1[e]^T + b1[e]). Block = 64 rows x 128 cols, 4 waves
// of 32x64. Fragments loaded straight from global (K contiguous), f32->f16 in
// registers. Latency hidden by TLP (no-LDS -> high wave residency).
__global__ __launch_bounds__(256) void gemm1_kernel(
        const float* __restrict__ inp, const int* __restrict__ tok_of_pos,
        const float* __restrict__ w1, const float* __restrict__ b1,
        const int* __restrict__ tile_e, const int* __restrict__ tile_row0,
        const int* __restrict__ tile_cnt, const int* __restrict__ ntiles,
        half_t* __restrict__ Y1) {
    const int t = blockIdx.x;
    if (t >= ntiles[0]) return;
    const int e = tile_e[t], row0 = tile_row0[t], cnt = tile_cnt[t];
    const int colbase = blockIdx.y * 128;
    const int tid = threadIdx.x;
    const int wave = tid >> 6, lane = tid & 63;
    const int quad = lane >> 4, l16 = lane & 15;
    const int wm = (wave & 1) * 32, wn = (wave >> 1) * 64;

    // per-thread operand row pointers (K contiguous, +quad*8 base k offset)
    const float* ap[2];
    #pragma unroll
    for (int mi = 0; mi < 2; mi++) {
        int ar = row0 + wm + mi * 16 + l16;
        if (ar > NP - 1) ar = NP - 1;
        ap[mi] = inp + (size_t)tok_of_pos[ar] * D_ + quad * 8;
    }
    const float* bp[4];
    #pragma unroll
    for (int ni = 0; ni < 4; ni++)
        bp[ni] = w1 + ((size_t)e * H_ + colbase + wn + ni * 16 + l16) * D_ + quad * 8;

    floatx4 acc[2][4] = {};
    for (int k0 = 0; k0 < D_; k0 += 64) {
        half8 ah[2][2];
        #pragma unroll
        for (int mi = 0; mi < 2; mi++)
            #pragma unroll
            for (int ks = 0; ks < 2; ks++) {
                const floatx4* pa = (const floatx4*)(ap[mi] + k0 + ks * 32);
                ah[mi][ks] = cvt8(pa[0], pa[1]);
            }
        #pragma unroll
        for (int ni = 0; ni < 4; ni++) {
            half8 bh[2];
            #pragma unroll
            for (int ks = 0; ks < 2; ks++) {
                const floatx4* pb = (const floatx4*)(bp[ni] + k0 + ks * 32);
                bh[ks] = cvt8(pb[0], pb[1]);
            }
            #pragma unroll
            for (int mi = 0; mi < 2; mi++)
                #pragma unroll
                for (int ks = 0; ks < 2; ks++)
                    acc[mi][ni] = __builtin_amdgcn_mfma_f32_16x16x32_f16(ah[mi][ks], bh[ks], acc[mi][ni], 0, 0, 0);
        }
    }

    float bias[4];
    #pragma unroll
    for (int ni = 0; ni < 4; ni++)
        bias[ni] = b1[(size_t)e * H_ + colbase + wn + ni * 16 + l16];
    #pragma unroll
    for (int mi = 0; mi < 2; mi++) {
        #pragma unroll
        for (int r = 0; r < 4; r++) {
            int rr = wm + mi * 16 + quad * 4 + r;
            if (rr >= cnt) continue;
            size_t rowoff = (size_t)(row0 + rr) * H_;
            #pragma unroll
            for (int ni = 0; ni < 4; ni++) {
                float v = acc[mi][ni][r] + bias[ni];
                Y1[rowoff + colbase + wn + ni * 16 + l16] = (half_t)gelu_f(v);
            }
        }
    }
}

// ---------------- GEMM2 (direct, split-K=2): Y2p[kz] = Y1 @ W2[e]^T ----------------
// Block = 64 rows x 64 cols, 4 waves of 32x32; A is f16 (no cvt), B f32->f16.
__global__ __launch_bounds__(256) void gemm2_kernel(
        const half_t* __restrict__ Y1, const float* __restrict__ w2,
        const int* __restrict__ tile_e, const int* __restrict__ tile_row0,
        const int* __restrict__ tile_cnt, const int* __restrict__ ntiles,
        float* __restrict__ Y2p) {
    const int t = blockIdx.x;
    if (t >= ntiles[0]) return;
    const int e = tile_e[t], row0 = tile_row0[t], cnt = tile_cnt[t];
    const int colbase = blockIdx.y * 64;
    const int kz = blockIdx.z;
    const int kzbase = kz * 1024;
    const int tid = threadIdx.x;
    const int wave = tid >> 6, lane = tid & 63;
    const int quad = lane >> 4, l16 = lane & 15;
    const int wm = (wave & 1) * 32, wn = (wave >> 1) * 32;

    const half_t* ap[2];
    #pragma unroll
    for (int mi = 0; mi < 2; mi++)
        ap[mi] = Y1 + (size_t)(row0 + wm + mi * 16 + l16) * H_ + kzbase + quad * 8;
    const float* bp[2];
    #pragma unroll
    for (int ni = 0; ni < 2; ni++)
        bp[ni] = w2 + ((size_t)e * D_ + colbase + wn + ni * 16 + l16) * H_ + kzbase + quad * 8;

    floatx4 acc[2][2] = {};
    for (int k0 = 0; k0 < 1024; k0 += 64) {
        half8 ah[2][2];
        #pragma unroll
        for (int mi = 0; mi < 2; mi++)
            #pragma unroll
            for (int ks = 0; ks < 2; ks++)
                ah[mi][ks] = *(const half8*)(ap[mi] + k0 + ks * 32);
        #pragma unroll
        for (int ni = 0; ni < 2; ni++) {
            half8 bh[2];
            #pragma unroll
            for (int ks = 0; ks < 2; ks++) {
                const floatx4* pb = (const floatx4*)(bp[ni] + k0 + ks * 32);
                bh[ks] = cvt8(pb[0], pb[1]);
            }
            #pragma unroll
            for (int mi = 0; mi < 2; mi++)
                #pragma unroll
                for (int ks = 0; ks < 2; ks++)
                    acc[mi][ni] = __builtin_amdgcn_mfma_f32_16x16x32_f16(ah[mi][ks], bh[ks], acc[mi][ni], 0, 0, 0);
        }
    }

    #pragma unroll
    for (int mi = 0; mi < 2; mi++) {
        #pragma unroll
        for (int r = 0; r < 4; r++) {
            int rr = wm + mi * 16 + quad * 4 + r;
            if (rr >= cnt) continue;
            size_t rowoff = ((size_t)kz * NP + row0 + rr) * D_;
            #pragma unroll
            for (int ni = 0; ni < 2; ni++)
                Y2p[rowoff + colbase + wn + ni * 16 + l16] = acc[mi][ni][r];
        }
    }
}

// ---------------- combine + bias + LayerNorm, wave per token ----------------
__global__ __launch_bounds__(256) void final_kernel(
        const float* __restrict__ Y2p, const float* __restrict__ b2,
        const int* __restrict__ idx, const float* __restrict__ score,
        const int* __restrict__ pos_of_pair,
        const float* __restrict__ ln_w, const float* __restrict__ ln_b,
        float* __restrict__ out) {
    int n = blockIdx.x * 4 + (threadIdx.x >> 6);
    int lane = threadIdx.x & 63;
    int p0 = pos_of_pair[2 * n], p1 = pos_of_pair[2 * n + 1];
    int e0 = idx[2 * n], e1 = idx[2 * n + 1];
    float s0 = score[2 * n], s1 = score[2 * n + 1];

    const floatx4* b2r0 = (const floatx4*)(b2 + (size_t)e0 * D_);
    const floatx4* b2r1 = (const floatx4*)(b2 + (size_t)e1 * D_);
    floatx4 a_lo = b2r0[lane * 2], a_hi = b2r0[lane * 2 + 1];
    floatx4 c_lo = b2r1[lane * 2], c_hi = b2r1[lane * 2 + 1];
    #pragma unroll
    for (int kz = 0; kz < 2; kz++) {
        const floatx4* r0 = (const floatx4*)(Y2p + ((size_t)kz * NP + p0) * D_);
        const floatx4* r1 = (const floatx4*)(Y2p + ((size_t)kz * NP + p1) * D_);
        a_lo += r0[lane * 2]; a_hi += r0[lane * 2 + 1];
        c_lo += r1[lane * 2]; c_hi += r1[lane * 2 + 1];
    }
    floatx4 y_lo = s0 * a_lo + s1 * c_lo;
    floatx4 y_hi = s0 * a_hi + s1 * c_hi;

    float s = 0.0f, q = 0.0f;
    #pragma unroll
    for (int j = 0; j < 4; j++) {
        s += y_lo[j] + y_hi[j];
        q += y_lo[j] * y_lo[j] + y_hi[j] * y_hi[j];
    }
    #pragma unroll
    for (int m = 1; m < 64; m <<= 1) {
        s += __shfl_xor(s, m);
        q += __shfl_xor(q, m);
    }
    float mean = s * (1.0f / 512.0f);
    float var = q * (1.0f / 512.0f) - mean * mean;
    float inv = 1.0f / sqrtf(var + 1e-5f);

    const floatx4* wv = (const floatx4*)ln_w;
    const floatx4* bv = (const floatx4*)ln_b;
    floatx4 o_lo = (y_lo - mean) * inv * wv[lane * 2]     + bv[lane * 2];
    floatx4 o_hi = (y_hi - mean) * inv * wv[lane * 2 + 1] + bv[lane * 2 + 1];
    floatx4* op = (floatx4*)(out + (size_t)n * D_);
    op[lane * 2] = o_lo;
    op[lane * 2 + 1] = o_hi;
}

extern "C" void kernel_launch(void* const* d_in, const int* in_sizes, int n_in,
                              void* d_out, int out_size, void* d_ws, size_t ws_size,
                              hipStream_t stream) {
    const float* inp    = (const float*)d_in[0];
    const float* gate_w = (const float*)d_in[1];
    const float* gate_b = (const float*)d_in[2];
    const float* w1     = (const float*)d_in[3];
    const float* b1     = (const float*)d_in[4];
    const float* w2     = (const float*)d_in[5];
    const float* b2     = (const float*)d_in[6];
    const float* ln_w   = (const float*)d_in[7];
    const float* ln_b   = (const float*)d_in[8];
    float* out = (float*)d_out;

    char* ws = (char*)d_ws;
    size_t o = 0;
    auto carve = [&](size_t bytes) -> char* {
        char* p = ws + o;
        o += (bytes + 255) & ~(size_t)255;
        return p;
    };
    half_t* Y1  = (half_t*)carve(sizeof(half_t) * (size_t)(NP + 128) * H_);  // slack rows
    float*  Y2p = (float*)carve(sizeof(float) * 2 * (size_t)NP * D_);        // 8.4 MB (split-K=2)
    float*  logits = (float*)carve(sizeof(float) * NTOK * E_);
    float*  score  = (float*)carve(sizeof(float) * NP);
    int* idx         = (int*)carve(sizeof(int) * NP);
    int* pos_of_pair = (int*)carve(sizeof(int) * NP);
    int* tok_of_pos  = (int*)carve(sizeof(int) * NP);
    int* tile_e      = (int*)carve(sizeof(int) * MAX_TILES);
    int* tile_row0   = (int*)carve(sizeof(int) * MAX_TILES);
    int* tile_cnt    = (int*)carve(sizeof(int) * MAX_TILES);
    int* ntiles      = (int*)carve(sizeof(int) * 1);

    gate_kernel<<<NTOK / 4, 256, 0, stream>>>(inp, gate_w, gate_b, logits);
    plan_kernel<<<1, 256, 0, stream>>>(logits, score, idx, pos_of_pair, tok_of_pos,
                                       tile_e, tile_row0, tile_cnt, ntiles);
    gemm1_kernel<<<dim3(MAX_TILES, H_ / 128), 256, 0, stream>>>(
        inp, tok_of_pos, w1, b1, tile_e, tile_row0, tile_cnt, ntiles, Y1);
    gemm2_kernel<<<dim3(MAX_TILES, D_ / 64, 2), 256, 0, stream>>>(
        Y1, w2, tile_e, tile_row0, tile_cnt, ntiles, Y2p);
    final_kernel<<<NTOK / 4, 256, 0, stream>>>(Y2p, b2, idx, score, pos_of_pair, ln_w, ln_b, out);
}

// Round 9
// 247.591 us; speedup vs baseline: 1.0146x; 1.0146x over previous
//
#include <hip/hip_runtime.h>
#include <cstdint>
#include <cstddef>

typedef _Float16 half_t;
typedef _Float16 half8 __attribute__((ext_vector_type(8)));
typedef float floatx4 __attribute__((ext_vector_type(4)));

#define E_ 8
#define D_ 512
#define H_ 2048
#define NTOK 1024
#define NP 2048            // NTOK * top_k
#define TM 64              // GEMM M-tile rows
#define MAX_TILES 40       // 2048/64 + 8 experts

__device__ __forceinline__ float gelu_f(float x) {
    return 0.5f * x * (1.0f + erff(x * 0.7071067811865476f));
}

__device__ __forceinline__ half8 cvt8(floatx4 a, floatx4 b) {
    half8 h = { (half_t)a[0], (half_t)a[1], (half_t)a[2], (half_t)a[3],
                (half_t)b[0], (half_t)b[1], (half_t)b[2], (half_t)b[3] };
    return h;
}

// ---------------- gate: logits only ----------------
__global__ __launch_bounds__(256) void gate_kernel(
        const float* __restrict__ inp, const float* __restrict__ gate_w,
        const float* __restrict__ gate_b, float* __restrict__ logits) {
    int n = blockIdx.x * 4 + (threadIdx.x >> 6);
    int lane = threadIdx.x & 63;
    const floatx4* xr = (const floatx4*)(inp + (size_t)n * D_);
    floatx4 x0 = xr[lane * 2], x1 = xr[lane * 2 + 1];
    #pragma unroll
    for (int e = 0; e < E_; e++) {
        const floatx4* gr = (const floatx4*)(gate_w + (size_t)e * D_);
        floatx4 g0 = gr[lane * 2], g1 = gr[lane * 2 + 1];
        float p = x0[0]*g0[0] + x0[1]*g0[1] + x0[2]*g0[2] + x0[3]*g0[3]
                + x1[0]*g1[0] + x1[1]*g1[1] + x1[2]*g1[2] + x1[3]*g1[3];
        #pragma unroll
        for (int m = 1; m < 64; m <<= 1) p += __shfl_xor(p, m);
        if (lane == 0) logits[(size_t)n * E_ + e] = p + gate_b[e];
    }
}

// ---------------- plan: top2/softmax/hist/offsets/tiles/pos maps ----------------
__global__ __launch_bounds__(256) void plan_kernel(
        const float* __restrict__ logits, float* __restrict__ score,
        int* __restrict__ idx, int* __restrict__ pos_of_pair,
        int* __restrict__ tok_of_pos,
        int* __restrict__ tile_e, int* __restrict__ tile_row0,
        int* __restrict__ tile_cnt, int* __restrict__ ntiles) {
    __shared__ int cnt_s[E_], off_s[E_ + 1], cur_s[E_];
    int tid = threadIdx.x;
    if (tid < E_) { cnt_s[tid] = 0; cur_s[tid] = 0; }
    __syncthreads();
    int my_e[4][2];
    #pragma unroll
    for (int i = 0; i < 4; i++) {
        int n = tid + i * 256;
        float l[E_];
        #pragma unroll
        for (int e = 0; e < E_; e++) l[e] = logits[(size_t)n * E_ + e];
        int e0 = 0; float v0 = l[0];
        #pragma unroll
        for (int e = 1; e < E_; e++) if (l[e] > v0) { v0 = l[e]; e0 = e; }
        int e1 = -1; float v1 = -3.4e38f;
        #pragma unroll
        for (int e = 0; e < E_; e++) if (e != e0 && l[e] > v1) { v1 = l[e]; e1 = e; }
        float s1 = expf(v1 - v0);
        float den = 1.0f + s1;
        score[2 * n]     = 1.0f / den;
        score[2 * n + 1] = s1 / den;
        idx[2 * n]     = e0;
        idx[2 * n + 1] = e1;
        atomicAdd(&cnt_s[e0], 1);
        atomicAdd(&cnt_s[e1], 1);
        my_e[i][0] = e0; my_e[i][1] = e1;
    }
    __syncthreads();
    if (tid == 0) {
        int o = 0;
        #pragma unroll
        for (int e = 0; e < E_; e++) { off_s[e] = o; o += cnt_s[e]; }
        off_s[E_] = o;
        int t = 0;
        for (int e = 0; e < E_; e++) {
            int c = cnt_s[e];
            int nt = (c + TM - 1) / TM;
            for (int i = 0; i < nt; i++) {
                tile_e[t] = e;
                tile_row0[t] = off_s[e] + i * TM;
                int rem = c - i * TM;
                tile_cnt[t] = rem < TM ? rem : TM;
                t++;
            }
        }
        ntiles[0] = t;
    }
    __syncthreads();
    #pragma unroll
    for (int i = 0; i < 4; i++) {
        #pragma unroll
        for (int k = 0; k < 2; k++) {
            int pp = (tid + i * 256) * 2 + k;
            int e = my_e[i][k];
            int r = atomicAdd(&cur_s[e], 1);
            int pos = off_s[e] + r;
            pos_of_pair[pp] = pos;
            tok_of_pos[pos] = pp >> 1;
        }
    }
}

// ---------------- GEMM1 (direct, no LDS, no barriers, XCD panel affinity) ----
// Y1 = gelu(inp[tok] @ W1[e]^T + b1[e]). Job (xcd, j): panel cb = xcd*4 + j/40
// (64 H-cols), tile t = j%40 (tile-minor => same B panel reused consecutively
// on the same XCD -> L2 hits). Block = 64x64, 4 waves of 32x32, fragments
// loaded straight from global, f32->f16 in registers.
__global__ __launch_bounds__(256) void gemm1_kernel(
        const float* __restrict__ inp, const int* __restrict__ tok_of_pos,
        const float* __restrict__ w1, const float* __restrict__ b1,
        const int* __restrict__ tile_e, const int* __restrict__ tile_row0,
        const int* __restrict__ tile_cnt, const int* __restrict__ ntiles,
        half_t* __restrict__ Y1) {
    const int bid = blockIdx.x;
    const int xcd = bid & 7, j = bid >> 3;      // 160 jobs per XCD
    const int t = j % MAX_TILES;                // tile varies fastest
    const int cb = xcd * 4 + j / MAX_TILES;     // 32 x 64-col panels
    if (t >= ntiles[0]) return;
    const int e = tile_e[t], row0 = tile_row0[t], cnt = tile_cnt[t];
    const int colbase = cb * 64;
    const int tid = threadIdx.x;
    const int wave = tid >> 6, lane = tid & 63;
    const int quad = lane >> 4, l16 = lane & 15;
    const int wm = (wave & 1) * 32, wn = (wave >> 1) * 32;

    const float* ap[2];
    #pragma unroll
    for (int mi = 0; mi < 2; mi++) {
        int ar = row0 + wm + mi * 16 + l16;
        if (ar > NP - 1) ar = NP - 1;
        ap[mi] = inp + (size_t)tok_of_pos[ar] * D_ + quad * 8;
    }
    const float* bp[2];
    #pragma unroll
    for (int ni = 0; ni < 2; ni++)
        bp[ni] = w1 + ((size_t)e * H_ + colbase + wn + ni * 16 + l16) * D_ + quad * 8;

    floatx4 acc[2][2] = {};
    #pragma unroll
    for (int k0 = 0; k0 < D_; k0 += 64) {
        half8 ah[2][2], bh[2][2];
        #pragma unroll
        for (int mi = 0; mi < 2; mi++)
            #pragma unroll
            for (int ks = 0; ks < 2; ks++) {
                const floatx4* pa = (const floatx4*)(ap[mi] + k0 + ks * 32);
                ah[mi][ks] = cvt8(pa[0], pa[1]);
            }
        #pragma unroll
        for (int ni = 0; ni < 2; ni++)
            #pragma unroll
            for (int ks = 0; ks < 2; ks++) {
                const floatx4* pb = (const floatx4*)(bp[ni] + k0 + ks * 32);
                bh[ni][ks] = cvt8(pb[0], pb[1]);
            }
        #pragma unroll
        for (int mi = 0; mi < 2; mi++)
            #pragma unroll
            for (int ni = 0; ni < 2; ni++)
                #pragma unroll
                for (int ks = 0; ks < 2; ks++)
                    acc[mi][ni] = __builtin_amdgcn_mfma_f32_16x16x32_f16(ah[mi][ks], bh[ni][ks], acc[mi][ni], 0, 0, 0);
    }

    float bias[2];
    #pragma unroll
    for (int ni = 0; ni < 2; ni++)
        bias[ni] = b1[(size_t)e * H_ + colbase + wn + ni * 16 + l16];
    #pragma unroll
    for (int mi = 0; mi < 2; mi++) {
        #pragma unroll
        for (int r = 0; r < 4; r++) {
            int rr = wm + mi * 16 + quad * 4 + r;
            if (rr >= cnt) continue;
            size_t rowoff = (size_t)(row0 + rr) * H_;
            #pragma unroll
            for (int ni = 0; ni < 2; ni++) {
                float v = acc[mi][ni][r] + bias[ni];
                Y1[rowoff + colbase + wn + ni * 16 + l16] = (half_t)gelu_f(v);
            }
        }
    }
}

// ---------------- GEMM2 (direct, split-K=4, XCD panel affinity) ----------------
// Y2p[kz] = Y1 @ W2[e]^T (kz K-slab). Job (xcd, j): panel p = xcd*4 + j/40,
// cb = p & 7 (64 D-cols), kz = p >> 3; tile t = j%40 (tile-minor).
__global__ __launch_bounds__(256) void gemm2_kernel(
        const half_t* __restrict__ Y1, const float* __restrict__ w2,
        const int* __restrict__ tile_e, const int* __restrict__ tile_row0,
        const int* __restrict__ tile_cnt, const int* __restrict__ ntiles,
        float* __restrict__ Y2p) {
    const int bid = blockIdx.x;
    const int xcd = bid & 7, j = bid >> 3;
    const int t = j % MAX_TILES;
    const int pnl = xcd * 4 + j / MAX_TILES;    // 32 panels = 8 cb x 4 kz
    const int cb = pnl & 7, kz = pnl >> 3;
    if (t >= ntiles[0]) return;
    const int e = tile_e[t], row0 = tile_row0[t], cnt = tile_cnt[t];
    const int colbase = cb * 64;
    const int kzbase = kz * 512;
    const int tid = threadIdx.x;
    const int wave = tid >> 6, lane = tid & 63;
    const int quad = lane >> 4, l16 = lane & 15;
    const int wm = (wave & 1) * 32, wn = (wave >> 1) * 32;

    const half_t* ap[2];
    #pragma unroll
    for (int mi = 0; mi < 2; mi++)
        ap[mi] = Y1 + (size_t)(row0 + wm + mi * 16 + l16) * H_ + kzbase + quad * 8;
    const float* bp[2];
    #pragma unroll
    for (int ni = 0; ni < 2; ni++)
        bp[ni] = w2 + ((size_t)e * D_ + colbase + wn + ni * 16 + l16) * H_ + kzbase + quad * 8;

    floatx4 acc[2][2] = {};
    #pragma unroll
    for (int k0 = 0; k0 < 512; k0 += 64) {
        half8 ah[2][2], bh[2][2];
        #pragma unroll
        for (int mi = 0; mi < 2; mi++)
            #pragma unroll
            for (int ks = 0; ks < 2; ks++)
                ah[mi][ks] = *(const half8*)(ap[mi] + k0 + ks * 32);
        #pragma unroll
        for (int ni = 0; ni < 2; ni++)
            #pragma unroll
            for (int ks = 0; ks < 2; ks++) {
                const floatx4* pb = (const floatx4*)(bp[ni] + k0 + ks * 32);
                bh[ni][ks] = cvt8(pb[0], pb[1]);
            }
        #pragma unroll
        for (int mi = 0; mi < 2; mi++)
            #pragma unroll
            for (int ni = 0; ni < 2; ni++)
                #pragma unroll
                for (int ks = 0; ks < 2; ks++)
                    acc[mi][ni] = __builtin_amdgcn_mfma_f32_16x16x32_f16(ah[mi][ks], bh[ni][ks], acc[mi][ni], 0, 0, 0);
    }

    #pragma unroll
    for (int mi = 0; mi < 2; mi++) {
        #pragma unroll
        for (int r = 0; r < 4; r++) {
            int rr = wm + mi * 16 + quad * 4 + r;
            if (rr >= cnt) continue;
            size_t rowoff = ((size_t)kz * NP + row0 + rr) * D_;
            #pragma unroll
            for (int ni = 0; ni < 2; ni++)
                Y2p[rowoff + colbase + wn + ni * 16 + l16] = acc[mi][ni][r];
        }
    }
}

// ---------------- combine + bias + LayerNorm, wave per token ----------------
__global__ __launch_bounds__(256) void final_kernel(
        const float* __restrict__ Y2p, const float* __restrict__ b2,
        const int* __restrict__ idx, const float* __restrict__ score,
        const int* __restrict__ pos_of_pair,
        const float* __restrict__ ln_w, const float* __restrict__ ln_b,
        float* __restrict__ out) {
    int n = blockIdx.x * 4 + (threadIdx.x >> 6);
    int lane = threadIdx.x & 63;
    int p0 = pos_of_pair[2 * n], p1 = pos_of_pair[2 * n + 1];
    int e0 = idx[2 * n], e1 = idx[2 * n + 1];
    float s0 = score[2 * n], s1 = score[2 * n + 1];

    const floatx4* b2r0 = (const floatx4*)(b2 + (size_t)e0 * D_);
    const floatx4* b2r1 = (const floatx4*)(b2 + (size_t)e1 * D_);
    floatx4 a_lo = b2r0[lane * 2], a_hi = b2r0[lane * 2 + 1];
    floatx4 c_lo = b2r1[lane * 2], c_hi = b2r1[lane * 2 + 1];
    #pragma unroll
    for (int kz = 0; kz < 4; kz++) {
        const floatx4* r0 = (const floatx4*)(Y2p + ((size_t)kz * NP + p0) * D_);
        const floatx4* r1 = (const floatx4*)(Y2p + ((size_t)kz * NP + p1) * D_);
        a_lo += r0[lane * 2]; a_hi += r0[lane * 2 + 1];
        c_lo += r1[lane * 2]; c_hi += r1[lane * 2 + 1];
    }
    floatx4 y_lo = s0 * a_lo + s1 * c_lo;
    floatx4 y_hi = s0 * a_hi + s1 * c_hi;

    float s = 0.0f, q = 0.0f;
    #pragma unroll
    for (int j = 0; j < 4; j++) {
        s += y_lo[j] + y_hi[j];
        q += y_lo[j] * y_lo[j] + y_hi[j] * y_hi[j];
    }
    #pragma unroll
    for (int m = 1; m < 64; m <<= 1) {
        s += __shfl_xor(s, m);
        q += __shfl_xor(q, m);
    }
    float mean = s * (1.0f / 512.0f);
    float var = q * (1.0f / 512.0f) - mean * mean;
    float inv = 1.0f / sqrtf(var + 1e-5f);

    const floatx4* wv = (const floatx4*)ln_w;
    const floatx4* bv = (const floatx4*)ln_b;
    floatx4 o_lo = (y_lo - mean) * inv * wv[lane * 2]     + bv[lane * 2];
    floatx4 o_hi = (y_hi - mean) * inv * wv[lane * 2 + 1] + bv[lane * 2 + 1];
    floatx4* op = (floatx4*)(out + (size_t)n * D_);
    op[lane * 2] = o_lo;
    op[lane * 2 + 1] = o_hi;
}

extern "C" void kernel_launch(void* const* d_in, const int* in_sizes, int n_in,
                              void* d_out, int out_size, void* d_ws, size_t ws_size,
                              hipStream_t stream) {
    const float* inp    = (const float*)d_in[0];
    const float* gate_w = (const float*)d_in[1];
    const float* gate_b = (const float*)d_in[2];
    const float* w1     = (const float*)d_in[3];
    const float* b1     = (const float*)d_in[4];
    const float* w2     = (const float*)d_in[5];
    const float* b2     = (const float*)d_in[6];
    const float* ln_w   = (const float*)d_in[7];
    const float* ln_b   = (const float*)d_in[8];
    float* out = (float*)d_out;

    char* ws = (char*)d_ws;
    size_t o = 0;
    auto carve = [&](size_t bytes) -> char* {
        char* p = ws + o;
        o += (bytes + 255) & ~(size_t)255;
        return p;
    };
    half_t* Y1  = (half_t*)carve(sizeof(half_t) * (size_t)(NP + 128) * H_);  // slack rows
    float*  Y2p = (float*)carve(sizeof(float) * 4 * (size_t)NP * D_);        // 16.8 MB (split-K=4)
    float*  logits = (float*)carve(sizeof(float) * NTOK * E_);
    float*  score  = (float*)carve(sizeof(float) * NP);
    int* idx         = (int*)carve(sizeof(int) * NP);
    int* pos_of_pair = (int*)carve(sizeof(int) * NP);
    int* tok_of_pos  = (int*)carve(sizeof(int) * NP);
    int* tile_e      = (int*)carve(sizeof(int) * MAX_TILES);
    int* tile_row0   = (int*)carve(sizeof(int) * MAX_TILES);
    int* tile_cnt    = (int*)carve(sizeof(int) * MAX_TILES);
    int* ntiles      = (int*)carve(sizeof(int) * 1);

    gate_kernel<<<NTOK / 4, 256, 0, stream>>>(inp, gate_w, gate_b, logits);
    plan_kernel<<<1, 256, 0, stream>>>(logits, score, idx, pos_of_pair, tok_of_pos,
                                       tile_e, tile_row0, tile_cnt, ntiles);
    // 1280 blocks: 8 XCD chunks x 4 panels x 40 tiles (tile-minor)
    gemm1_kernel<<<MAX_TILES * 32, 256, 0, stream>>>(
        inp, tok_of_pos, w1, b1, tile_e, tile_row0, tile_cnt, ntiles, Y1);
    gemm2_kernel<<<MAX_TILES * 32, 256, 0, stream>>>(
        Y1, w2, tile_e, tile_row0, tile_cnt, ntiles, Y2p);
    final_kernel<<<NTOK / 4, 256, 0, stream>>>(Y2p, b2, idx, score, pos_of_pair, ln_w, ln_b, out);
}